// Round 4
// baseline (4950.454 us; speedup 1.0000x reference)
//
#include <hip/hip_runtime.h>

// ---------------------------------------------------------------------------
// ManualLSTM: B=32, S=512, H=1024.
//   Phase A: xg = bf16(x) @ bf16(Wi)  -> bf16 [16384][4096]  (bias in phase B)
//   Phase B: persistent 128-block kernel, 512 timesteps.
//     Cross-block h via relaxed AGENT-scope atomics (sc0 sc1, LLC-coherent).
//     R4: A-operand (h) MFMA fragments are loaded DIRECTLY from the packed
//     global h image into registers (64x8B coherent loads/lane) — no LDS
//     h staging, one fewer barrier, load latency overlaps MFMA via compiler
//     vmcnt scheduling. R3's staged gather serialized: all 64KB had to land
//     in LDS + barrier before the first MFMA could issue.
// ---------------------------------------------------------------------------

typedef __attribute__((ext_vector_type(4))) float f32x4_t;
typedef __attribute__((ext_vector_type(8))) short bf16x8_t;
typedef unsigned long long ull_t;

#define HID   1024
#define SLEN  512
#define BATCH 32
#define NGATE 4096
#define MROWS 16384          // 32*512

// ws layout (bytes)
#define XG_OFF    0ULL                      // 16384*4096*2 = 134217728
#define XB_OFF    134217728ULL              // 16384*1024*2 = 33554432
#define WIT_OFF   167772160ULL              // 4096*1024*2  = 8388608
#define WHT_OFF   176160768ULL              // 4096*1024*2  = 8388608
#define HBUF_OFF  184549376ULL              // 2 * 65536 (packed bf16 [32][1024])
#define FLAGS_OFF 184680448ULL              // 128 flags * 16B stride = 2048B

#define HIMG_G      65536                   // packed global h image: 32*1024*2
#define HROW_STRIDE 2064                    // LDS W rows: 2048B + 16B pad
#define NBLK_B      128                     // persistent blocks
#define FLAG_STRIDE 4                       // in dwords (16B)

// persistent-kernel LDS layout (h image eliminated)
#define W_OFF_L   0                         // 32*2064 = 66048
#define G_OFF_L   66048                     // gates: 32 rows * 33 f32 = 4224B
#define LDS_TOTAL 70272

__device__ __forceinline__ unsigned short f2bf(float f) {
  unsigned u = __float_as_uint(f);
  u += 0x7fffu + ((u >> 16) & 1u);          // round-nearest-even
  return (unsigned short)(u >> 16);
}
__device__ __forceinline__ float bf2f(unsigned short u) {
  return __uint_as_float(((unsigned)u) << 16);
}
__device__ __forceinline__ float fast_rcp(float x) { return __builtin_amdgcn_rcpf(x); }
__device__ __forceinline__ float sigmoid_f(float x) { return fast_rcp(1.f + __expf(-x)); }
__device__ __forceinline__ float tanh_f(float x) { return 1.f - 2.f * fast_rcp(1.f + __expf(2.f * x)); }

// ---------------------------------------------------------------- converters
__global__ __launch_bounds__(256) void conv_x_bf16(const float* __restrict__ in,
                                                   unsigned short* __restrict__ out) {
  size_t i = (size_t)blockIdx.x * 256 + threadIdx.x;
  const float4* p = (const float4*)in;
  float4 v = p[i];
  ushort4 o;
  o.x = f2bf(v.x); o.y = f2bf(v.y); o.z = f2bf(v.z); o.w = f2bf(v.w);
  ((ushort4*)out)[i] = o;
}

// in: fp32 [1024][4096]  -> out: bf16 [4096][1024]  (out[n][k] = in[k][n])
__global__ void transpose_w_bf16(const float* __restrict__ in,
                                 unsigned short* __restrict__ out) {
  __shared__ float tile[32][33];
  int tx = threadIdx.x, ty = threadIdx.y;        // block (32, 8)
  int n0 = blockIdx.x * 32, k0 = blockIdx.y * 32;
  #pragma unroll
  for (int i = 0; i < 4; i++)
    tile[ty + 8 * i][tx] = in[(size_t)(k0 + ty + 8 * i) * NGATE + n0 + tx];
  __syncthreads();
  #pragma unroll
  for (int i = 0; i < 4; i++)
    out[(size_t)(n0 + ty + 8 * i) * HID + k0 + tx] = f2bf(tile[tx][ty + 8 * i]);
}

__global__ void init_ws(unsigned* __restrict__ himg0, unsigned* __restrict__ flags) {
  size_t i = (size_t)blockIdx.x * 256 + threadIdx.x;   // 16384 threads
  himg0[i] = 0u;                                       // HIMG_G/4 = 16384 dwords
  if (i < NBLK_B * FLAG_STRIDE) flags[i] = 0u;
}

// ---------------------------------------------------------------- Phase A
// C[16384][4096] bf16 = A[16384][1024] bf16  x  BT[4096][1024] bf16
__global__ __launch_bounds__(256) void gemm_xg(const unsigned short* __restrict__ A,
                                               const unsigned short* __restrict__ BT,
                                               unsigned short* __restrict__ C) {
  extern __shared__ char smem[];
  char* As = smem;                 // 128 rows * 80B (32 bf16 + 16B pad)
  char* Bs = smem + 10240;
  const int tid = threadIdx.x;
  const int lane = tid & 63, w = tid >> 6, q = lane >> 4, l16 = lane & 15;
  const int wm = w & 1, wn = w >> 1;
  const size_t m0 = (size_t)blockIdx.y * 128, n0 = (size_t)blockIdx.x * 128;

  f32x4_t acc[4][4];
  #pragma unroll
  for (int i = 0; i < 4; i++)
    #pragma unroll
    for (int j = 0; j < 4; j++) acc[i][j] = (f32x4_t){0.f, 0.f, 0.f, 0.f};

  for (int kk = 0; kk < 32; kk++) {
    const int k0 = kk * 32;
    #pragma unroll
    for (int h = 0; h < 2; h++) {
      int idx = tid + h * 256;              // 0..511
      int r = idx >> 2, ch = idx & 3;
      uint4 va = *(const uint4*)((const char*)A + ((m0 + r) * HID + k0) * 2 + ch * 16);
      *(uint4*)(As + r * 80 + ch * 16) = va;
      uint4 vb = *(const uint4*)((const char*)BT + ((n0 + r) * HID + k0) * 2 + ch * 16);
      *(uint4*)(Bs + r * 80 + ch * 16) = vb;
    }
    __syncthreads();
    bf16x8_t af[4], bf[4];
    #pragma unroll
    for (int mt = 0; mt < 4; mt++)
      af[mt] = *(const bf16x8_t*)(As + (wm * 64 + mt * 16 + l16) * 80 + q * 16);
    #pragma unroll
    for (int nt = 0; nt < 4; nt++)
      bf[nt] = *(const bf16x8_t*)(Bs + (wn * 64 + nt * 16 + l16) * 80 + q * 16);
    #pragma unroll
    for (int mt = 0; mt < 4; mt++)
      #pragma unroll
      for (int nt = 0; nt < 4; nt++)
        acc[mt][nt] = __builtin_amdgcn_mfma_f32_16x16x32_bf16(af[mt], bf[nt], acc[mt][nt], 0, 0, 0);
    __syncthreads();
  }

  // epilogue: stage C tile (bf16 [128][136]) through LDS for coalesced stores
  unsigned short* cst = (unsigned short*)smem;
  #pragma unroll
  for (int mt = 0; mt < 4; mt++)
    #pragma unroll
    for (int nt = 0; nt < 4; nt++)
      #pragma unroll
      for (int r = 0; r < 4; r++) {
        int m = wm * 64 + mt * 16 + q * 4 + r;
        int n = wn * 64 + nt * 16 + l16;
        cst[m * 136 + n] = f2bf(acc[mt][nt][r]);
      }
  __syncthreads();
  #pragma unroll
  for (int i = 0; i < 8; i++) {
    int idx = tid + i * 256;                // < 2048
    int row = idx >> 4, ch = idx & 15;
    uint4 v = *(const uint4*)((const char*)cst + row * 272 + ch * 16);
    *(uint4*)((char*)C + ((m0 + row) * NGATE + n0) * 2 + ch * 16) = v;
  }
}

// ---------------------------------------------------------------- Phase B
// Persistent recurrence. 128 blocks x 256 threads. Block owns 8 h-columns.
__global__ __launch_bounds__(256) void lstm_persistent(
    const unsigned short* __restrict__ xg,   // [16384][4096] bf16
    const unsigned short* __restrict__ whT,  // [4096][1024] bf16
    const float* __restrict__ bias,          // [4096]
    float* __restrict__ out,                 // [32][512][1024]
    unsigned short* hbuf,                    // 2 packed images, 65536B each
    unsigned* flags) {                       // [128] @ 16B stride
  extern __shared__ char smem[];
  char* w_lds = smem + W_OFF_L;
  float* gates = (float*)(smem + G_OFF_L);         // [32][33] f32

  const int tid = threadIdx.x;
  const int lane = tid & 63, w = tid >> 6, q = lane >> 4, l16 = lane & 15;
  const int Mt = w & 1, Nt = w >> 1;
  const int hcol0 = blockIdx.x * 8;
  const int b_ew = tid >> 3, j_ew = tid & 7;

  // pin Wh slice in LDS: lds row n (= g*8+j) <- whT row g*1024 + hcol0 + j
  for (int idx = tid; idx < 32 * 128; idx += 256) {
    int n = idx >> 7, ch = idx & 127;
    size_t gr = (size_t)((n >> 3) << 10) + hcol0 + (n & 7);
    uint4 v = *(const uint4*)((const char*)whT + gr * 2048 + ch * 16);
    *(uint4*)(w_lds + n * HROW_STRIDE + ch * 16) = v;
  }
  float bs[4];
  #pragma unroll
  for (int g = 0; g < 4; g++) bs[g] = bias[g * 1024 + hcol0 + j_ew];
  float c_st = 0.f;
  // A-fragment source index within packed h image (ull granules):
  // lane needs 16B fragments at row(Mt*16+l16)*2048 + q*16 + m*64, m=0..31
  const int abase = (Mt * 16 + l16) * 256 + q * 2;
  const char* brow = w_lds + (Nt * 16 + l16) * HROW_STRIDE + q * 16;
  __syncthreads();

  for (int t = 0; t < SLEN; t++) {
    // prefetch xg for this step (no h dependency) — overlaps the flag wait
    unsigned short xgv[4];
    {
      const unsigned short* p = xg + ((size_t)((b_ew << 9) + t) << 12) + hcol0 + j_ew;
      xgv[0] = p[0]; xgv[1] = p[1024]; xgv[2] = p[2048]; xgv[3] = p[3072];
    }
    if (t > 0) {
      if (tid < NBLK_B) {
        const unsigned* fp = flags + tid * FLAG_STRIDE;
        while (__hip_atomic_load(fp, __ATOMIC_RELAXED, __HIP_MEMORY_SCOPE_AGENT) < (unsigned)t)
          __builtin_amdgcn_s_sleep(1);
      }
      __syncthreads();
      asm volatile("" ::: "memory");
    }

    // A-fragments straight from the LLC-coherent packed h image (no LDS stage)
    ull_t* src = (ull_t*)(hbuf + (size_t)(t & 1) * (HIMG_G / 2));
    bf16x8_t a_frag[32];
    #pragma unroll
    for (int m = 0; m < 32; m++) {
      union { ull_t u[2]; bf16x8_t v; } cvt;
      cvt.u[0] = __hip_atomic_load(src + abase + m * 8, __ATOMIC_RELAXED,
                                   __HIP_MEMORY_SCOPE_AGENT);
      cvt.u[1] = __hip_atomic_load(src + abase + m * 8 + 1, __ATOMIC_RELAXED,
                                   __HIP_MEMORY_SCOPE_AGENT);
      a_frag[m] = cvt.v;
    }

    // gates[b][n] = sum_k h[b][k] * Wslice[k][n]; 2 acc chains for ILP
    f32x4_t acc0 = (f32x4_t){0.f, 0.f, 0.f, 0.f};
    f32x4_t acc1 = (f32x4_t){0.f, 0.f, 0.f, 0.f};
    #pragma unroll
    for (int m = 0; m < 32; m += 2) {
      bf16x8_t b0 = *(const bf16x8_t*)(brow + m * 64);
      acc0 = __builtin_amdgcn_mfma_f32_16x16x32_bf16(a_frag[m], b0, acc0, 0, 0, 0);
      bf16x8_t b1 = *(const bf16x8_t*)(brow + m * 64 + 64);
      acc1 = __builtin_amdgcn_mfma_f32_16x16x32_bf16(a_frag[m + 1], b1, acc1, 0, 0, 0);
    }
    #pragma unroll
    for (int r = 0; r < 4; r++) {
      int bb = Mt * 16 + q * 4 + r;
      int nn = Nt * 16 + l16;
      gates[bb * 33 + nn] = acc0[r] + acc1[r];
    }
    __syncthreads();

    // elementwise: thread owns (b_ew, j_ew)
    float gi = gates[b_ew * 33 + j_ew]      + bs[0] + bf2f(xgv[0]);
    float gf = gates[b_ew * 33 + 8 + j_ew]  + bs[1] + bf2f(xgv[1]);
    float gg = gates[b_ew * 33 + 16 + j_ew] + bs[2] + bf2f(xgv[2]);
    float go = gates[b_ew * 33 + 24 + j_ew] + bs[3] + bf2f(xgv[3]);
    float i_s = sigmoid_f(gi), f_s = sigmoid_f(gf);
    float g_t = tanh_f(gg), o_s = sigmoid_f(go);
    c_st = f_s * c_st + i_s * g_t;
    float h = o_s * tanh_f(c_st);

    // publish h: per-thread coherent 2B store, drain own wave's stores,
    // barrier (all waves drained), then RELAXED flag store. No wbl2/inv.
    unsigned short* hnext = hbuf + (size_t)((t + 1) & 1) * (HIMG_G / 2);
    __hip_atomic_store(hnext + b_ew * HID + hcol0 + j_ew, f2bf(h),
                       __ATOMIC_RELAXED, __HIP_MEMORY_SCOPE_AGENT);
    asm volatile("s_waitcnt vmcnt(0)" ::: "memory");
    __syncthreads();
    if (tid == 0)
      __hip_atomic_store(flags + blockIdx.x * FLAG_STRIDE, (unsigned)(t + 1),
                         __ATOMIC_RELAXED, __HIP_MEMORY_SCOPE_AGENT);
    // out store is NOT read by other blocks — keep it off the critical path
    out[((size_t)b_ew * SLEN + t) * HID + hcol0 + j_ew] = h;
  }
}

// ---------------------------------------------------------------- launcher
extern "C" void kernel_launch(void* const* d_in, const int* in_sizes, int n_in,
                              void* d_out, int out_size, void* d_ws, size_t ws_size,
                              hipStream_t stream) {
  const float* x    = (const float*)d_in[0];   // [32,512,1024]
  const float* wi   = (const float*)d_in[1];   // [1024,4096]
  const float* wh   = (const float*)d_in[2];   // [1024,4096]
  const float* bias = (const float*)d_in[3];   // [4096]
  float* out = (float*)d_out;

  char* ws = (char*)d_ws;
  unsigned short* xg   = (unsigned short*)(ws + XG_OFF);
  unsigned short* xb   = (unsigned short*)(ws + XB_OFF);
  unsigned short* wiT  = (unsigned short*)(ws + WIT_OFF);
  unsigned short* whT  = (unsigned short*)(ws + WHT_OFF);
  unsigned short* hbuf = (unsigned short*)(ws + HBUF_OFF);
  unsigned* flags      = (unsigned*)(ws + FLAGS_OFF);

  (void)hipFuncSetAttribute((const void*)lstm_persistent,
                            hipFuncAttributeMaxDynamicSharedMemorySize,
                            LDS_TOTAL);

  conv_x_bf16<<<16384, 256, 0, stream>>>(x, xb);
  transpose_w_bf16<<<dim3(128, 32), dim3(32, 8), 0, stream>>>(wi, wiT);
  transpose_w_bf16<<<dim3(128, 32), dim3(32, 8), 0, stream>>>(wh, whT);
  init_ws<<<64, 256, 0, stream>>>((unsigned*)hbuf, flags);
  gemm_xg<<<dim3(32, 128), 256, 34816, stream>>>(xb, wiT, xg);
  lstm_persistent<<<NBLK_B, 256, LDS_TOTAL, stream>>>(xg, whT, bias, out, hbuf, flags);
}

// Round 6
// 2814.908 us; speedup vs baseline: 1.7587x; 1.7587x over previous
//
#include <hip/hip_runtime.h>

// ---------------------------------------------------------------------------
// ManualLSTM: B=32, S=512, H=1024.
//   Phase A: xg = bf16(x) @ bf16(Wi)  -> bf16 [16384][4096]  (bias in phase B)
//   Phase B: persistent recurrence, 4 INDEPENDENT groups x 64 blocks.
//     Group g owns batches 8g..8g+7 and the full 4096-gate dim; block m of a
//     group owns hidden cols m*16..+16 (64 gate-cols, Wh slice 128KB in LDS).
//     Per-step sync is GROUP-local: 16KB h image, 64 flags. Cross-block h via
//     relaxed AGENT-scope atomics (LLC-coherent); ordering = vmcnt(0) drain +
//     barrier + relaxed flag store (R3-validated). No threadfence/release
//     (buffer_wbl2/inv L2 walks).
//   R6 = R5 with the h-gather index fix: group image rows are 2048B = 256
//     ulls (row = idx>>8, col = idx&255). R5's >>7/&127 wrote 32KB into a
//     16.5KB LDS region, clobbering gates + OOB -> NaN.
// ---------------------------------------------------------------------------

typedef __attribute__((ext_vector_type(4))) float f32x4_t;
typedef __attribute__((ext_vector_type(8))) short bf16x8_t;
typedef unsigned long long ull_t;

#define HID   1024
#define SLEN  512
#define NGATE 4096

// ws layout (bytes)
#define XG_OFF    0ULL                      // 16384*4096*2 = 134217728
#define XB_OFF    134217728ULL              // 16384*1024*2 = 33554432
#define WIT_OFF   167772160ULL              // 4096*1024*2  = 8388608
#define WHT_OFF   176160768ULL              // 4096*1024*2  = 8388608
#define HBUF_OFF  184549376ULL              // 4 groups * 2 bufs * 16384B = 131072
#define FLAGS_OFF 184680448ULL              // 256 flags * 16B stride = 4096B

#define NBLK_B      256                     // 4 groups x 64 blocks
#define FLAG_STRIDE 4                       // dwords (16B)

// persistent-kernel LDS layout
#define W_OFF_L   0                         // 64 rows * 2064B = 132096
#define H_OFF_L   132096                    // 8 rows * 2064B  = 16512
#define G_OFF_L   148608                    // gates [16][65] f32 = 4160
#define LDS_TOTAL 152768

__device__ __forceinline__ unsigned short f2bf(float f) {
  unsigned u = __float_as_uint(f);
  u += 0x7fffu + ((u >> 16) & 1u);          // round-nearest-even
  return (unsigned short)(u >> 16);
}
__device__ __forceinline__ float bf2f(unsigned short u) {
  return __uint_as_float(((unsigned)u) << 16);
}
__device__ __forceinline__ float fast_rcp(float x) { return __builtin_amdgcn_rcpf(x); }
__device__ __forceinline__ float sigmoid_f(float x) { return fast_rcp(1.f + __expf(-x)); }
__device__ __forceinline__ float tanh_f(float x) { return 1.f - 2.f * fast_rcp(1.f + __expf(2.f * x)); }

// ---------------------------------------------------------------- converters
__global__ __launch_bounds__(256) void conv_x_bf16(const float* __restrict__ in,
                                                   unsigned short* __restrict__ out) {
  size_t i = (size_t)blockIdx.x * 256 + threadIdx.x;
  const float4* p = (const float4*)in;
  float4 v = p[i];
  ushort4 o;
  o.x = f2bf(v.x); o.y = f2bf(v.y); o.z = f2bf(v.z); o.w = f2bf(v.w);
  ((ushort4*)out)[i] = o;
}

// in: fp32 [1024][4096]  -> out: bf16 [4096][1024]  (out[n][k] = in[k][n])
__global__ void transpose_w_bf16(const float* __restrict__ in,
                                 unsigned short* __restrict__ out) {
  __shared__ float tile[32][33];
  int tx = threadIdx.x, ty = threadIdx.y;        // block (32, 8)
  int n0 = blockIdx.x * 32, k0 = blockIdx.y * 32;
  #pragma unroll
  for (int i = 0; i < 4; i++)
    tile[ty + 8 * i][tx] = in[(size_t)(k0 + ty + 8 * i) * NGATE + n0 + tx];
  __syncthreads();
  #pragma unroll
  for (int i = 0; i < 4; i++)
    out[(size_t)(n0 + ty + 8 * i) * HID + k0 + tx] = f2bf(tile[tx][ty + 8 * i]);
}

__global__ void init_ws(unsigned* __restrict__ himg, unsigned* __restrict__ flags) {
  size_t i = (size_t)blockIdx.x * 256 + threadIdx.x;   // 16384 threads
  himg[i] = 0u;                // zero all 4 groups' double-buffered h images
  himg[i + 16384] = 0u;        // (32768 dwords total)
  if (i < NBLK_B * FLAG_STRIDE) flags[i] = 0u;
}

// ---------------------------------------------------------------- Phase A
// C[16384][4096] bf16 = A[16384][1024] bf16  x  BT[4096][1024] bf16
__global__ __launch_bounds__(256) void gemm_xg(const unsigned short* __restrict__ A,
                                               const unsigned short* __restrict__ BT,
                                               unsigned short* __restrict__ C) {
  extern __shared__ char smem[];
  char* As = smem;                 // 128 rows * 80B (32 bf16 + 16B pad)
  char* Bs = smem + 10240;
  const int tid = threadIdx.x;
  const int lane = tid & 63, w = tid >> 6, q = lane >> 4, l16 = lane & 15;
  const int wm = w & 1, wn = w >> 1;
  const size_t m0 = (size_t)blockIdx.y * 128, n0 = (size_t)blockIdx.x * 128;

  f32x4_t acc[4][4];
  #pragma unroll
  for (int i = 0; i < 4; i++)
    #pragma unroll
    for (int j = 0; j < 4; j++) acc[i][j] = (f32x4_t){0.f, 0.f, 0.f, 0.f};

  for (int kk = 0; kk < 32; kk++) {
    const int k0 = kk * 32;
    #pragma unroll
    for (int h = 0; h < 2; h++) {
      int idx = tid + h * 256;              // 0..511
      int r = idx >> 2, ch = idx & 3;
      uint4 va = *(const uint4*)((const char*)A + ((m0 + r) * HID + k0) * 2 + ch * 16);
      *(uint4*)(As + r * 80 + ch * 16) = va;
      uint4 vb = *(const uint4*)((const char*)BT + ((n0 + r) * HID + k0) * 2 + ch * 16);
      *(uint4*)(Bs + r * 80 + ch * 16) = vb;
    }
    __syncthreads();
    bf16x8_t af[4], bf[4];
    #pragma unroll
    for (int mt = 0; mt < 4; mt++)
      af[mt] = *(const bf16x8_t*)(As + (wm * 64 + mt * 16 + l16) * 80 + q * 16);
    #pragma unroll
    for (int nt = 0; nt < 4; nt++)
      bf[nt] = *(const bf16x8_t*)(Bs + (wn * 64 + nt * 16 + l16) * 80 + q * 16);
    #pragma unroll
    for (int mt = 0; mt < 4; mt++)
      #pragma unroll
      for (int nt = 0; nt < 4; nt++)
        acc[mt][nt] = __builtin_amdgcn_mfma_f32_16x16x32_bf16(af[mt], bf[nt], acc[mt][nt], 0, 0, 0);
    __syncthreads();
  }

  // epilogue: stage C tile (bf16 [128][136]) through LDS for coalesced stores
  unsigned short* cst = (unsigned short*)smem;
  #pragma unroll
  for (int mt = 0; mt < 4; mt++)
    #pragma unroll
    for (int nt = 0; nt < 4; nt++)
      #pragma unroll
      for (int r = 0; r < 4; r++) {
        int m = wm * 64 + mt * 16 + q * 4 + r;
        int n = wn * 64 + nt * 16 + l16;
        cst[m * 136 + n] = f2bf(acc[mt][nt][r]);
      }
  __syncthreads();
  #pragma unroll
  for (int i = 0; i < 8; i++) {
    int idx = tid + i * 256;                // < 2048
    int row = idx >> 4, ch = idx & 15;
    uint4 v = *(const uint4*)((const char*)cst + row * 272 + ch * 16);
    *(uint4*)((char*)C + ((m0 + row) * NGATE + n0) * 2 + ch * 16) = v;
  }
}

// ---------------------------------------------------------------- Phase B
// 4 groups x 64 blocks x 256 threads. Group = 8 batches, full gate dim.
// Block m: hidden cols m*16..+16 => local gate cols n = G*16+j, G=0..3.
__global__ __launch_bounds__(256) void lstm_persistent(
    const unsigned short* __restrict__ xg,   // [16384][4096] bf16
    const unsigned short* __restrict__ whT,  // [4096][1024] bf16
    const float* __restrict__ bias,          // [4096]
    float* __restrict__ out,                 // [32][512][1024]
    unsigned short* hbuf,                    // 4 groups * 2 bufs * [8][1024] bf16
    unsigned* flags) {                       // 256 @ 16B stride, group-major
  extern __shared__ char smem[];
  char* w_lds = smem + W_OFF_L;                    // [64 rows n][2048B k] +16B pad
  char* h_lds = smem + H_OFF_L;                    // [8 rows b][2048B k] +16B pad
  float* gates = (float*)(smem + G_OFF_L);         // [16][65] f32 (rows 8-15 dup)

  const int tid = threadIdx.x;
  const int lane = tid & 63, wv = tid >> 6, q = lane >> 4, l16 = lane & 15;
  const int g = blockIdx.x >> 6;                   // group 0..3
  const int m = blockIdx.x & 63;                   // member 0..63
  const int b_l = tid >> 4, j_l = tid & 15;        // EW mapping (tid<128)

  // pin Wh slice: LDS row n (= G*16+j) <- whT row G*1024 + m*16 + j
  for (int idx = tid; idx < 64 * 128; idx += 256) {
    int n = idx >> 7, ch = idx & 127;
    size_t gr = (size_t)(n >> 4) * 1024 + m * 16 + (n & 15);
    uint4 v = *(const uint4*)((const char*)whT + gr * 2048 + ch * 16);
    *(uint4*)(w_lds + n * 2064 + ch * 16) = v;
  }
  float bsr[4];
  #pragma unroll
  for (int G = 0; G < 4; G++) bsr[G] = bias[G * 1024 + m * 16 + j_l];
  float c_st = 0.f;
  const char* arow = h_lds + (l16 & 7) * 2064 + q * 16;   // rows 8-15 mirror 0-7
  const char* brow = w_lds + (wv * 16 + l16) * 2064 + q * 16;
  unsigned short* hb_g = hbuf + g * 16384;         // 2 bufs of 8192 shorts
  unsigned* fl_g = flags + g * 64 * FLAG_STRIDE;
  __syncthreads();

  for (int t = 0; t < SLEN; t++) {
    // xg prefetch (no h dependency) — overlaps the flag wait
    unsigned short xgv[4];
    if (tid < 128) {
      const unsigned short* p =
          xg + ((size_t)(g * 8 + b_l) * 512 + t) * 4096 + m * 16 + j_l;
      xgv[0] = p[0]; xgv[1] = p[1024]; xgv[2] = p[2048]; xgv[3] = p[3072];
    }
    if (t > 0) {
      if (tid < 64) {
        const unsigned* fp = fl_g + tid * FLAG_STRIDE;
        while (__hip_atomic_load(fp, __ATOMIC_RELAXED, __HIP_MEMORY_SCOPE_AGENT) < (unsigned)t)
          __builtin_amdgcn_s_sleep(1);
      }
      __syncthreads();
      asm volatile("" ::: "memory");
    }
    // gather group h image (16KB = 2048 ulls; rows are 2048B = 256 ulls):
    // coherent 8B loads -> padded LDS image
    {
      ull_t* src = (ull_t*)(hb_g + (t & 1) * 8192);
      #pragma unroll
      for (int pth = 0; pth < 8; pth++) {
        int idx = tid + pth * 256;                 // < 2048 ull
        ull_t v = __hip_atomic_load(src + idx, __ATOMIC_RELAXED,
                                    __HIP_MEMORY_SCOPE_AGENT);
        int row = idx >> 8, col = idx & 255;       // FIXED (R5 had >>7/&127)
        *(ull_t*)(h_lds + row * 2064 + col * 8) = v;
      }
    }
    __syncthreads();

    // gates[b][n] = sum_k h[b][k] * Wslice[k][n]; wave wv = N-tile wv
    f32x4_t acc0 = (f32x4_t){0.f, 0.f, 0.f, 0.f};
    f32x4_t acc1 = (f32x4_t){0.f, 0.f, 0.f, 0.f};
    #pragma unroll
    for (int kk = 0; kk < 32; kk += 2) {
      bf16x8_t a0 = *(const bf16x8_t*)(arow + kk * 64);
      bf16x8_t b0 = *(const bf16x8_t*)(brow + kk * 64);
      acc0 = __builtin_amdgcn_mfma_f32_16x16x32_bf16(a0, b0, acc0, 0, 0, 0);
      bf16x8_t a1 = *(const bf16x8_t*)(arow + kk * 64 + 64);
      bf16x8_t b1 = *(const bf16x8_t*)(brow + kk * 64 + 64);
      acc1 = __builtin_amdgcn_mfma_f32_16x16x32_bf16(a1, b1, acc1, 0, 0, 0);
    }
    #pragma unroll
    for (int r = 0; r < 4; r++) {
      int bb = q * 4 + r;                          // rows 8-15 are duplicates
      gates[bb * 65 + wv * 16 + l16] = acc0[r] + acc1[r];
    }
    __syncthreads();

    // elementwise: 128 threads own (b_l, j_l)
    if (tid < 128) {
      float gi = gates[b_l * 65 + j_l]      + bsr[0] + bf2f(xgv[0]);
      float gf = gates[b_l * 65 + 16 + j_l] + bsr[1] + bf2f(xgv[1]);
      float gg = gates[b_l * 65 + 32 + j_l] + bsr[2] + bf2f(xgv[2]);
      float go = gates[b_l * 65 + 48 + j_l] + bsr[3] + bf2f(xgv[3]);
      float i_s = sigmoid_f(gi), f_s = sigmoid_f(gf);
      float g_t = tanh_f(gg), o_s = sigmoid_f(go);
      c_st = f_s * c_st + i_s * g_t;
      float h = o_s * tanh_f(c_st);
      unsigned short* hnext = hb_g + ((t + 1) & 1) * 8192;
      __hip_atomic_store(hnext + b_l * 1024 + m * 16 + j_l, f2bf(h),
                         __ATOMIC_RELAXED, __HIP_MEMORY_SCOPE_AGENT);
      out[((size_t)(g * 8 + b_l) * 512 + t) * 1024 + m * 16 + j_l] = h;
    }
    // drain own wave's stores; barrier = all waves drained; then flag
    asm volatile("s_waitcnt vmcnt(0)" ::: "memory");
    __syncthreads();
    if (tid == 0)
      __hip_atomic_store(fl_g + m * FLAG_STRIDE, (unsigned)(t + 1),
                         __ATOMIC_RELAXED, __HIP_MEMORY_SCOPE_AGENT);
  }
}

// ---------------------------------------------------------------- launcher
extern "C" void kernel_launch(void* const* d_in, const int* in_sizes, int n_in,
                              void* d_out, int out_size, void* d_ws, size_t ws_size,
                              hipStream_t stream) {
  const float* x    = (const float*)d_in[0];   // [32,512,1024]
  const float* wi   = (const float*)d_in[1];   // [1024,4096]
  const float* wh   = (const float*)d_in[2];   // [1024,4096]
  const float* bias = (const float*)d_in[3];   // [4096]
  float* out = (float*)d_out;

  char* ws = (char*)d_ws;
  unsigned short* xg   = (unsigned short*)(ws + XG_OFF);
  unsigned short* xb   = (unsigned short*)(ws + XB_OFF);
  unsigned short* wiT  = (unsigned short*)(ws + WIT_OFF);
  unsigned short* whT  = (unsigned short*)(ws + WHT_OFF);
  unsigned short* hbuf = (unsigned short*)(ws + HBUF_OFF);
  unsigned* flags      = (unsigned*)(ws + FLAGS_OFF);

  (void)hipFuncSetAttribute((const void*)lstm_persistent,
                            hipFuncAttributeMaxDynamicSharedMemorySize,
                            LDS_TOTAL);

  conv_x_bf16<<<16384, 256, 0, stream>>>(x, xb);
  transpose_w_bf16<<<dim3(128, 32), dim3(32, 8), 0, stream>>>(wi, wiT);
  transpose_w_bf16<<<dim3(128, 32), dim3(32, 8), 0, stream>>>(wh, whT);
  init_ws<<<64, 256, 0, stream>>>((unsigned*)hbuf, flags);
  gemm_xg<<<dim3(32, 128), 256, 34816, stream>>>(xb, wiT, xg);
  lstm_persistent<<<NBLK_B, 256, LDS_TOTAL, stream>>>(xg, whT, bias, out, hbuf, flags);
}